// Round 7
// baseline (488.588 us; speedup 1.0000x reference)
//
#include <hip/hip_runtime.h>

// ---------------------------------------------------------------------------
// STGCN forward, MI355X. Internal compute bf16-MFMA / fp32-accum.
// TC1 -> (dense-L build) -> prop GEMM x2 -> cheb combine -> TC2-as-GEMM+stats
// -> BN finalize. T2 never materialized (only per-node stats + t''=7 slice).
// LDS tiles use XOR slot-swizzle (pre-swizzled global source, swizzled read).
// tc2 v3: 512-thread / 8-wave blocks, A[256][192] staged ONCE (96 KB),
// cho fused inside block, W double-buffered 24 KB chunks. Cuts L2/L3 staging
// traffic 750 MB -> 274 MB and raises per-wave MFMA 144 -> 864.
// ---------------------------------------------------------------------------

typedef __bf16 bf16;
typedef __bf16 bf16x8 __attribute__((ext_vector_type(8)));
typedef float  f32x4  __attribute__((ext_vector_type(4)));

__device__ __forceinline__ f32x4 mfma16(bf16x8 a, bf16x8 b, f32x4 c) {
  return __builtin_amdgcn_mfma_f32_16x16x32_bf16(a, b, c, 0, 0, 0);
}
__device__ __forceinline__ f32x4 splat4(float v) { f32x4 t = {v, v, v, v}; return t; }

// async global->LDS, 16B per lane; lds base must be wave-uniform (lane*16 auto)
__device__ __forceinline__ void lds_load16(const bf16* g, bf16* l) {
  __builtin_amdgcn_global_load_lds((const __attribute__((address_space(1))) void*)g,
                                   (__attribute__((address_space(3))) void*)l, 16, 0, 0);
}

#define NN 1024
#define EE 16384

// --------------------------- edge preprocessing ----------------------------
__global__ __launch_bounds__(256) void deg_kernel(const int* __restrict__ ei,
                                                  const float* __restrict__ ew,
                                                  float* __restrict__ deg) {
  int e = blockIdx.x * 256 + threadIdx.x;
  int r = ei[e], c = ei[EE + e];
  if (r != c) atomicAdd(&deg[r], ew[e]);
}

// L[col][row] += -dinv[row]*w*dinv[col]  (dense 1024x1024 fp32)
__global__ __launch_bounds__(256) void scatterL_kernel(const int* __restrict__ ei,
                                                       const float* __restrict__ ew,
                                                       const float* __restrict__ deg,
                                                       float* __restrict__ Lf) {
  int e = blockIdx.x * 256 + threadIdx.x;
  int r = ei[e], c = ei[EE + e];
  float w = (r == c) ? 0.0f : ew[e];
  float dr = deg[r], dc = deg[c];
  float ir = dr > 0.0f ? rsqrtf(dr) : 0.0f;
  float ic = dc > 0.0f ? rsqrtf(dc) : 0.0f;
  float norm = -(ir * w * ic);
  if (norm != 0.0f) atomicAdd(&Lf[(size_t)c * NN + r], norm);
}

__global__ __launch_bounds__(256) void cvtL_kernel(const float* __restrict__ Lf,
                                                   bf16* __restrict__ Lbf) {
  int i = blockIdx.x * 256 + threadIdx.x;
  Lbf[i] = (bf16)Lf[i];
}

// ------------------------------ weight prep --------------------------------
// Wc (fp32, 192x64): rows [0:64)=W0-W2, [64:128)=W1, [128:192)=2*W2
// W2c (bf16, [1152 cols][192 k]): col = og*48 + conv*16 + oo  (o = og*16+oo)
//   k = kk*64 + h ; value = w_conv[(o*64+h)*3 + kk]
__global__ __launch_bounds__(256) void wprep_kernel(const float* __restrict__ W,
                                                    const float* __restrict__ w21,
                                                    const float* __restrict__ w22,
                                                    const float* __restrict__ w23,
                                                    float* __restrict__ Wc,
                                                    bf16* __restrict__ W2c) {
  int i = blockIdx.x * 256 + threadIdx.x;   // 912*256 = 233472 = 12288 + 221184 exact
  if (i < 12288) {
    int row = i >> 6, j = i & 63;
    int src = row >> 6, h = row & 63;
    float v;
    if (src == 0)      v = W[h * 64 + j] - W[2 * 4096 + h * 64 + j];
    else if (src == 1) v = W[4096 + h * 64 + j];
    else               v = 2.0f * W[2 * 4096 + h * 64 + j];
    Wc[i] = v;
  } else {
    int j2 = i - 12288;                      // [0, 221184)
    int c = j2 / 192, k = j2 % 192;
    int og = c / 48, r48 = c % 48;
    int conv = r48 >> 4, oo = r48 & 15;
    int o = og * 16 + oo;
    int kk = k >> 6, h = k & 63;
    const float* ws = (conv == 0) ? w21 : (conv == 1) ? w22 : w23;
    W2c[j2] = (bf16)ws[(o * 64 + h) * 3 + kk];
  }
}

// ------------------------------- TC1 ---------------------------------------
// zf[(b*10+t)*64+h][n] = relu(P*sigmoid(Q)+R), feature-major bf16
__global__ __launch_bounds__(256) void tc1_kernel(const float* __restrict__ X,
                                                  const float* __restrict__ w1, const float* __restrict__ c1,
                                                  const float* __restrict__ w2, const float* __restrict__ c2,
                                                  const float* __restrict__ w3, const float* __restrict__ c3,
                                                  bf16* __restrict__ zf) {
  int row = blockIdx.y;                       // (b*10+t)*64+h, [0,10240)
  int n = blockIdx.x * 256 + threadIdx.x;
  int h = row & 63, bt = row >> 6;
  int t = bt % 10, b = bt / 10;
  float P = c1[h], Q = c2[h], R = c3[h];
  const float* xb = X + (size_t)(b * 1024 + n) * 24;   // (B,N,C=2,T=12)
  #pragma unroll
  for (int c = 0; c < 2; c++)
    #pragma unroll
    for (int k = 0; k < 3; k++) {
      float xv = xb[c * 12 + t + k];
      int wi = (h * 2 + c) * 3 + k;
      P += xv * w1[wi]; Q += xv * w2[wi]; R += xv * w3[wi];
    }
  float Hv = P * (1.0f / (1.0f + __expf(-Q))) + R;
  Hv = Hv > 0.0f ? Hv : 0.0f;
  zf[(size_t)row * NN + n] = (bf16)Hv;
}

// --------------------------- B^T GEMM (bf16) -------------------------------
// C[M][Nc] = A[M][K] * Bt[Nc][K]^T ; 128x128 tile, BK=64, global_load_lds.
// LDS rows of 64 bf16 = 8 slots of 16B; physical slot = logical ^ (row&7).
__global__ __launch_bounds__(256) void gemm_bt(const bf16* __restrict__ A,
                                               const bf16* __restrict__ Bt,
                                               bf16* __restrict__ C,
                                               int M, int Nc, int K) {
  __shared__ __align__(16) bf16 As[8192];
  __shared__ __align__(16) bf16 Bs[8192];
  const int tid = threadIdx.x, lane = tid & 63, w = tid >> 6;
  const int wm = w >> 1, wn = w & 1;
  const int m0 = blockIdx.y * 128, n0 = blockIdx.x * 128;
  const int colL = lane & 15, kg = lane >> 4;
  const int rxor = colL & 7;                 // row&7 for all fragment rows

  f32x4 acc[4][4];
  #pragma unroll
  for (int i = 0; i < 4; i++)
    #pragma unroll
    for (int j = 0; j < 4; j++) acc[i][j] = splat4(0.0f);

  for (int kb = 0; kb < K; kb += 64) {
    if (kb) __syncthreads();
    #pragma unroll
    for (int i = 0; i < 4; i++) {
      int e = (w * 4 + i) * 512 + lane * 8;
      int row = e >> 6, s = (e >> 3) & 7;
      int ksw = ((s ^ (row & 7)) << 3);      // pre-swizzled source slot
      lds_load16(&A[(size_t)(m0 + row) * K + kb + ksw], &As[(w * 4 + i) * 512]);
      lds_load16(&Bt[(size_t)(n0 + row) * K + kb + ksw], &Bs[(w * 4 + i) * 512]);
    }
    __syncthreads();
    #pragma unroll
    for (int kk = 0; kk < 2; kk++) {
      bf16x8 af[4], bfr[4];
      #pragma unroll
      for (int mt = 0; mt < 4; mt++)
        af[mt] = *(const bf16x8*)(&As[(wm * 64 + mt * 16 + colL) * 64 +
                                      (((kk * 4 + kg) ^ rxor) << 3)]);
      #pragma unroll
      for (int nt = 0; nt < 4; nt++)
        bfr[nt] = *(const bf16x8*)(&Bs[(wn * 64 + nt * 16 + colL) * 64 +
                                       (((kk * 4 + kg) ^ rxor) << 3)]);
      #pragma unroll
      for (int mt = 0; mt < 4; mt++)
        #pragma unroll
        for (int nt = 0; nt < 4; nt++)
          acc[mt][nt] = mfma16(af[mt], bfr[nt], acc[mt][nt]);
    }
  }
  #pragma unroll
  for (int mt = 0; mt < 4; mt++)
    #pragma unroll
    for (int nt = 0; nt < 4; nt++) {
      int m = m0 + wm * 64 + mt * 16 + kg * 4;
      int n = n0 + wn * 64 + nt * 16 + colL;
      #pragma unroll
      for (int r = 0; r < 4; r++)
        C[(size_t)(m + r) * Nc + n] = (bf16)acc[mt][nt][r];
    }
}

// ------------------------- cheb combine (vector) ---------------------------
// Tg[n][b][t][j] = relu(cheb_b[j] + sum_h z*Wc[0:64] + P1*Wc[64:128] + P2*Wc[128:192])
// Wave w owns j-quarter jg=w (16 channels) -> acc[16] in VGPRs, weights via s_load.
__global__ __launch_bounds__(256) void combine_kernel(const bf16* __restrict__ zf,
                                                      const bf16* __restrict__ P1f,
                                                      const bf16* __restrict__ P2f,
                                                      const float* __restrict__ Wc,
                                                      const float* __restrict__ chebb,
                                                      bf16* __restrict__ Tg) {
  const int slab = blockIdx.y;                 // bt in [0,160)
  const int b = slab / 10, t = slab % 10;
  const int lane = threadIdx.x & 63;
  const int jg = __builtin_amdgcn_readfirstlane(threadIdx.x >> 6);  // wave-uniform
  const int n = blockIdx.x * 64 + lane;

  float acc[16];
  #pragma unroll
  for (int j = 0; j < 16; j++) acc[j] = chebb[jg * 16 + j];

  const size_t zoff = (size_t)(slab * 64) * NN + n;
  #pragma unroll 1
  for (int src = 0; src < 3; src++) {
    const bf16* Z = (src == 0) ? zf : (src == 1) ? P1f : P2f;
    const float* wsrc = Wc + (size_t)(src * 64) * 64 + jg * 16;
    #pragma unroll 4
    for (int h = 0; h < 64; h++) {
      float v = (float)Z[zoff + (size_t)h * NN];
      const float* wr = wsrc + h * 64;         // uniform -> s_load
      #pragma unroll
      for (int j = 0; j < 16; j++) acc[j] += v * wr[j];
    }
  }

  bf16 tmp[16];
  #pragma unroll
  for (int j = 0; j < 16; j++) {
    float x = acc[j];
    tmp[j] = (bf16)(x > 0.0f ? x : 0.0f);
  }
  size_t base = (size_t)((n * 16 + b) * 10 + t) * 64 + jg * 16;
  *(bf16x8*)(&Tg[base])     = *(const bf16x8*)(&tmp[0]);
  *(bf16x8*)(&Tg[base + 8]) = *(const bf16x8*)(&tmp[8]);
}

// ----------------------- TC2 as GEMM + fused BN stats ----------------------
// C[131072 x 1152] = TgWin[131072 x 192] * W2c^T.
// Block: 256 rows (nodes) at fixed (b,tpp), ALL 1152 cols via cho=0..5 loop.
// 8 waves (wm=w>>1 row-slice, wn=w&1 col-half); per wave 64 rows x 96 cols/cho.
// LDS: A[256][192] (96 KB, staged once, slot-swizzled rows of 24 slots) +
//      W double-buffer 2 x [192][64] (24 KB each). 144 KB total, 1 block/CU.
__global__ __launch_bounds__(512) void tc2_kernel(const bf16* __restrict__ Tg,
                                                  const bf16* __restrict__ W2c,
                                                  const float* __restrict__ b1,
                                                  const float* __restrict__ b2,
                                                  const float* __restrict__ b3,
                                                  float* __restrict__ nsum,
                                                  float* __restrict__ nsq,
                                                  bf16* __restrict__ slice) {
  __shared__ __align__(16) char smem[147456];  // A 96K + 2 x W 24K
  bf16* Asm = (bf16*)smem;
  const int rb = blockIdx.x;                   // 512 blocks: b(16) x tpp(8) x nch(4)
  const int b = rb >> 5, tpp = (rb >> 2) & 7, n0 = (rb & 3) << 8;
  const int tid = threadIdx.x, lane = tid & 63, w = tid >> 6;
  const int wm = w >> 1, wn = w & 1;
  const int colL = lane & 15, kg = lane >> 4;
  const int rxor = colL & 7;

  // ---- stage A once: 96 KB; wave w stages bytes [w*12288, +12288)
  #pragma unroll
  for (int i = 0; i < 12; i++) {
    int fb = w * 12288 + i * 1024 + lane * 16;  // byte offset in A region
    int row = fb / 384;                          // 384 B per row (192 bf16)
    int s = (fb % 384) >> 4;                     // slot 0..23
    int koff = (s & ~7) * 8 + (((s & 7) ^ (row & 7)) << 3);
    lds_load16(&Tg[(size_t)((n0 + row) * 16 + b) * 640 + tpp * 64 + koff],
               (bf16*)(smem + w * 12288 + i * 1024));
  }
  // ---- W chunk stager: 24 KB = [192 cols][64 k], rows of 8 slots
  auto stageW = [&](int cho, int ks, int buf) {
    #pragma unroll
    for (int i = 0; i < 3; i++) {
      int fb = w * 3072 + i * 1024 + lane * 16;
      int col = fb >> 7;
      int s8 = (fb >> 4) & 7;
      lds_load16(&W2c[(size_t)(cho * 192 + col) * 192 + ks * 64 + ((s8 ^ (col & 7)) << 3)],
                 (bf16*)(smem + 98304 + buf * 24576 + w * 3072 + i * 1024));
    }
  };
  stageW(0, 0, 0);
  __syncthreads();                             // A + W0 ready

  float ssum[4][4], ssq[4][4];
  #pragma unroll
  for (int mt = 0; mt < 4; mt++)
    #pragma unroll
    for (int r = 0; r < 4; r++) { ssum[mt][r] = 0.0f; ssq[mt][r] = 0.0f; }

  #pragma unroll
  for (int cho = 0; cho < 6; cho++) {
    f32x4 acc[4][6];
    #pragma unroll
    for (int i = 0; i < 4; i++)
      #pragma unroll
      for (int j = 0; j < 6; j++) acc[i][j] = splat4(0.0f);

    #pragma unroll
    for (int ks = 0; ks < 3; ks++) {
      const int p = cho * 3 + ks;
      if (p < 17) stageW((p + 1) / 3, (p + 1) % 3, (p + 1) & 1);  // prefetch
      const bf16* Wsb = (const bf16*)(smem + 98304 + (p & 1) * 24576);
      #pragma unroll
      for (int kk = 0; kk < 2; kk++) {
        bf16x8 af[4], bfr[6];
        #pragma unroll
        for (int mt = 0; mt < 4; mt++)
          af[mt] = *(const bf16x8*)(&Asm[(wm * 64 + mt * 16 + colL) * 192 + ks * 64 +
                                         (((kk * 4 + kg) ^ rxor) << 3)]);
        #pragma unroll
        for (int j = 0; j < 6; j++)
          bfr[j] = *(const bf16x8*)(&Wsb[(wn * 96 + j * 16 + colL) * 64 +
                                         (((kk * 4 + kg) ^ rxor) << 3)]);
        #pragma unroll
        for (int mt = 0; mt < 4; mt++)
          #pragma unroll
          for (int j = 0; j < 6; j++)
            acc[mt][j] = mfma16(af[mt], bfr[j], acc[mt][j]);
      }
      __syncthreads();                         // drain prefetch + frag reads
    }

    // GLU epilogue for this cho (registers only)
    #pragma unroll
    for (int g = 0; g < 2; g++) {
      int o = ((cho * 4 + wn * 2 + g) << 4) + colL;
      float bv1 = b1[o], bv2 = b2[o], bv3 = b3[o];
      #pragma unroll
      for (int mt = 0; mt < 4; mt++)
        #pragma unroll
        for (int r = 0; r < 4; r++) {
          float p  = acc[mt][g * 3 + 0][r] + bv1;
          float q  = acc[mt][g * 3 + 1][r] + bv2;
          float rr = acc[mt][g * 3 + 2][r] + bv3;
          float h = p * (1.0f / (1.0f + __expf(-q))) + rr;
          h = h > 0.0f ? h : 0.0f;
          ssum[mt][r] += h;
          ssq[mt][r] += h * h;
          if (tpp == 7) {
            int n = n0 + wm * 64 + mt * 16 + kg * 4 + r;
            slice[(size_t)((b << 10) + n) * 384 + o] = (bf16)h;
          }
        }
    }
  }

  // reduce over colL (16 lanes) -> LDS -> 2 atomics per row (256 rows)
  float* sred = (float*)smem;                  // alias A region (done with it)
  sred[tid] = 0.0f;                            // 512 floats = [256][2]
  __syncthreads();
  #pragma unroll
  for (int mt = 0; mt < 4; mt++)
    #pragma unroll
    for (int r = 0; r < 4; r++) {
      float s = ssum[mt][r], q = ssq[mt][r];
      #pragma unroll
      for (int d = 1; d < 16; d <<= 1) {
        s += __shfl_xor(s, d);
        q += __shfl_xor(q, d);
      }
      if (colL == 0) {
        int rl = wm * 64 + mt * 16 + kg * 4 + r;   // local row [0,256)
        atomicAdd(&sred[rl * 2], s);
        atomicAdd(&sred[rl * 2 + 1], q);
      }
    }
  __syncthreads();
  if (tid < 256) {
    atomicAdd(&nsum[n0 + tid], sred[tid * 2]);
    atomicAdd(&nsq[n0 + tid], sred[tid * 2 + 1]);
  }
}

// ----------------------------- BN finalize ---------------------------------
__global__ __launch_bounds__(256) void bnstat_kernel(const float* __restrict__ nsum,
                                                     const float* __restrict__ nsq,
                                                     const float* __restrict__ gamma,
                                                     const float* __restrict__ beta,
                                                     float* __restrict__ scoff) {
  int n = blockIdx.x * 256 + threadIdx.x;       // 1024 exact
  const float inv_cnt = 1.0f / 49152.0f;        // B*8*384
  float m = nsum[n] * inv_cnt;
  float var = nsq[n] * inv_cnt - m * m;
  float sc = rsqrtf(var + 1e-5f) * gamma[n];
  scoff[n] = sc;
  scoff[1024 + n] = beta[n] - m * sc;
}

// out[f], f = c*16384 + b*1024 + n  (== reshape(T,B,N,OUT) flat order)
__global__ __launch_bounds__(256) void final_kernel(const bf16* __restrict__ slice,
                                                    const float* __restrict__ scoff,
                                                    float* __restrict__ out) {
  int f = blockIdx.x * 256 + threadIdx.x;       // 6291456 exact
  int c = f >> 14, rem = f & 16383;
  int b = rem >> 10, n = rem & 1023;
  out[f] = (float)slice[(size_t)((b << 10) + n) * 384 + c] * scoff[n] + scoff[1024 + n];
}

// ---------------------------------------------------------------------------
extern "C" void kernel_launch(void* const* d_in, const int* in_sizes, int n_in,
                              void* d_out, int out_size, void* d_ws, size_t ws_size,
                              hipStream_t stream) {
  const float* X    = (const float*)d_in[0];
  const int*   ei   = (const int*)d_in[1];
  const float* ew   = (const float*)d_in[2];
  const float* t1w1 = (const float*)d_in[3];
  const float* t1b1 = (const float*)d_in[4];
  const float* t1w2 = (const float*)d_in[5];
  const float* t1b2 = (const float*)d_in[6];
  const float* t1w3 = (const float*)d_in[7];
  const float* t1b3 = (const float*)d_in[8];
  const float* chebW = (const float*)d_in[9];
  const float* chebB = (const float*)d_in[10];
  const float* t2w1 = (const float*)d_in[11];
  const float* t2b1 = (const float*)d_in[12];
  const float* t2w2 = (const float*)d_in[13];
  const float* t2b2 = (const float*)d_in[14];
  const float* t2w3 = (const float*)d_in[15];
  const float* t2b3 = (const float*)d_in[16];
  const float* gamma = (const float*)d_in[17];
  const float* beta  = (const float*)d_in[18];
  float* out = (float*)d_out;

  char* ws = (char*)d_ws;
  float* Lf    = (float*)(ws);                  // 4 MB dense L (fp32 scatter target)
  float* deg   = (float*)(ws + 4194304);
  float* nsum  = (float*)(ws + 4198400);
  float* nsq   = (float*)(ws + 4202496);
  bf16*  Lbf   = (bf16*)(ws + 4210688);         // 2 MB
  bf16*  zf    = (bf16*)(ws + 6307840);         // 20 MB feature-major z
  bf16*  P1f   = (bf16*)(ws + 27279360);        // 20 MB
  bf16*  P2f   = (bf16*)(ws + 48250880);        // 20 MB
  bf16*  Tg    = (bf16*)(ws + 69222400);        // 20 MB node-major
  float* Wc    = (float*)(ws + 90193920);       // 48 KB combined cheb weights
  bf16*  W2c   = (bf16*)(ws + 90243072);        // 432 KB tc2 weights [col][k]
  bf16*  slice = (bf16*)(ws + 90685440);        // 12 MB t''=7 slice
  float* scoff = (float*)(ws + 103268352);      // 8 KB

  hipMemsetAsync(ws, 0, 4206592, stream);       // Lf + deg + nsum + nsq

  wprep_kernel<<<912, 256, 0, stream>>>(chebW, t2w1, t2w2, t2w3, Wc, W2c);
  tc1_kernel<<<dim3(4, 10240), 256, 0, stream>>>(X, t1w1, t1b1, t1w2, t1b2, t1w3, t1b3, zf);
  deg_kernel<<<64, 256, 0, stream>>>(ei, ew, deg);
  scatterL_kernel<<<64, 256, 0, stream>>>(ei, ew, deg, Lf);
  cvtL_kernel<<<4096, 256, 0, stream>>>(Lf, Lbf);
  gemm_bt<<<dim3(8, 80), 256, 0, stream>>>(zf, Lbf, P1f, 10240, 1024, 1024);
  gemm_bt<<<dim3(8, 80), 256, 0, stream>>>(P1f, Lbf, P2f, 10240, 1024, 1024);
  combine_kernel<<<dim3(16, 160), 256, 0, stream>>>(zf, P1f, P2f, Wc, chebB, Tg);
  tc2_kernel<<<512, 512, 0, stream>>>(Tg, W2c, t2b1, t2b2, t2b3, nsum, nsq, slice);
  bnstat_kernel<<<4, 256, 0, stream>>>(nsum, nsq, gamma, beta, scoff);
  final_kernel<<<24576, 256, 0, stream>>>(slice, scoff, out);
}

// Round 8
// 481.499 us; speedup vs baseline: 1.0147x; 1.0147x over previous
//
#include <hip/hip_runtime.h>

// ---------------------------------------------------------------------------
// STGCN forward, MI355X. Internal compute bf16-MFMA / fp32-accum.
// TC1 -> (dense-L build) -> prop GEMM x2 -> cheb combine -> TC2-as-GEMM+stats
// -> BN finalize. T2 never materialized (only per-node stats + t''=7 slice).
// LDS tiles use XOR slot-swizzle (pre-swizzled global source, swizzled read).
// tc2 v3.1: 512-thread / 8-wave blocks, A[256][192] staged ONCE (96 KB),
// cho fused in-block, W double-buffered. __launch_bounds__(512,2) -> 256-VGPR
// budget (LDS already caps at 1 block/CU); R6's 128-VGPR spill eliminated.
// ---------------------------------------------------------------------------

typedef __bf16 bf16;
typedef __bf16 bf16x8 __attribute__((ext_vector_type(8)));
typedef float  f32x4  __attribute__((ext_vector_type(4)));

__device__ __forceinline__ f32x4 mfma16(bf16x8 a, bf16x8 b, f32x4 c) {
  return __builtin_amdgcn_mfma_f32_16x16x32_bf16(a, b, c, 0, 0, 0);
}
__device__ __forceinline__ f32x4 splat4(float v) { f32x4 t = {v, v, v, v}; return t; }

// async global->LDS, 16B per lane; lds base must be wave-uniform (lane*16 auto)
__device__ __forceinline__ void lds_load16(const bf16* g, bf16* l) {
  __builtin_amdgcn_global_load_lds((const __attribute__((address_space(1))) void*)g,
                                   (__attribute__((address_space(3))) void*)l, 16, 0, 0);
}

#define NN 1024
#define EE 16384

// --------------------------- edge preprocessing ----------------------------
__global__ __launch_bounds__(256) void deg_kernel(const int* __restrict__ ei,
                                                  const float* __restrict__ ew,
                                                  float* __restrict__ deg) {
  int e = blockIdx.x * 256 + threadIdx.x;
  int r = ei[e], c = ei[EE + e];
  if (r != c) atomicAdd(&deg[r], ew[e]);
}

// L[col][row] += -dinv[row]*w*dinv[col]  (dense 1024x1024 fp32)
__global__ __launch_bounds__(256) void scatterL_kernel(const int* __restrict__ ei,
                                                       const float* __restrict__ ew,
                                                       const float* __restrict__ deg,
                                                       float* __restrict__ Lf) {
  int e = blockIdx.x * 256 + threadIdx.x;
  int r = ei[e], c = ei[EE + e];
  float w = (r == c) ? 0.0f : ew[e];
  float dr = deg[r], dc = deg[c];
  float ir = dr > 0.0f ? rsqrtf(dr) : 0.0f;
  float ic = dc > 0.0f ? rsqrtf(dc) : 0.0f;
  float norm = -(ir * w * ic);
  if (norm != 0.0f) atomicAdd(&Lf[(size_t)c * NN + r], norm);
}

__global__ __launch_bounds__(256) void cvtL_kernel(const float* __restrict__ Lf,
                                                   bf16* __restrict__ Lbf) {
  int i = blockIdx.x * 256 + threadIdx.x;
  Lbf[i] = (bf16)Lf[i];
}

// ------------------------------ weight prep --------------------------------
// Wc (fp32, 192x64): rows [0:64)=W0-W2, [64:128)=W1, [128:192)=2*W2
// W2c (bf16, [1152 cols][192 k]): col = og*48 + conv*16 + oo  (o = og*16+oo)
//   k = kk*64 + h ; value = w_conv[(o*64+h)*3 + kk]
__global__ __launch_bounds__(256) void wprep_kernel(const float* __restrict__ W,
                                                    const float* __restrict__ w21,
                                                    const float* __restrict__ w22,
                                                    const float* __restrict__ w23,
                                                    float* __restrict__ Wc,
                                                    bf16* __restrict__ W2c) {
  int i = blockIdx.x * 256 + threadIdx.x;   // 912*256 = 233472 = 12288 + 221184 exact
  if (i < 12288) {
    int row = i >> 6, j = i & 63;
    int src = row >> 6, h = row & 63;
    float v;
    if (src == 0)      v = W[h * 64 + j] - W[2 * 4096 + h * 64 + j];
    else if (src == 1) v = W[4096 + h * 64 + j];
    else               v = 2.0f * W[2 * 4096 + h * 64 + j];
    Wc[i] = v;
  } else {
    int j2 = i - 12288;                      // [0, 221184)
    int c = j2 / 192, k = j2 % 192;
    int og = c / 48, r48 = c % 48;
    int conv = r48 >> 4, oo = r48 & 15;
    int o = og * 16 + oo;
    int kk = k >> 6, h = k & 63;
    const float* ws = (conv == 0) ? w21 : (conv == 1) ? w22 : w23;
    W2c[j2] = (bf16)ws[(o * 64 + h) * 3 + kk];
  }
}

// ------------------------------- TC1 ---------------------------------------
// zf[(b*10+t)*64+h][n] = relu(P*sigmoid(Q)+R), feature-major bf16
__global__ __launch_bounds__(256) void tc1_kernel(const float* __restrict__ X,
                                                  const float* __restrict__ w1, const float* __restrict__ c1,
                                                  const float* __restrict__ w2, const float* __restrict__ c2,
                                                  const float* __restrict__ w3, const float* __restrict__ c3,
                                                  bf16* __restrict__ zf) {
  int row = blockIdx.y;                       // (b*10+t)*64+h, [0,10240)
  int n = blockIdx.x * 256 + threadIdx.x;
  int h = row & 63, bt = row >> 6;
  int t = bt % 10, b = bt / 10;
  float P = c1[h], Q = c2[h], R = c3[h];
  const float* xb = X + (size_t)(b * 1024 + n) * 24;   // (B,N,C=2,T=12)
  #pragma unroll
  for (int c = 0; c < 2; c++)
    #pragma unroll
    for (int k = 0; k < 3; k++) {
      float xv = xb[c * 12 + t + k];
      int wi = (h * 2 + c) * 3 + k;
      P += xv * w1[wi]; Q += xv * w2[wi]; R += xv * w3[wi];
    }
  float Hv = P * (1.0f / (1.0f + __expf(-Q))) + R;
  Hv = Hv > 0.0f ? Hv : 0.0f;
  zf[(size_t)row * NN + n] = (bf16)Hv;
}

// --------------------------- B^T GEMM (bf16) -------------------------------
// C[M][Nc] = A[M][K] * Bt[Nc][K]^T ; 128x128 tile, BK=64, global_load_lds.
// LDS rows of 64 bf16 = 8 slots of 16B; physical slot = logical ^ (row&7).
__global__ __launch_bounds__(256) void gemm_bt(const bf16* __restrict__ A,
                                               const bf16* __restrict__ Bt,
                                               bf16* __restrict__ C,
                                               int M, int Nc, int K) {
  __shared__ __align__(16) bf16 As[8192];
  __shared__ __align__(16) bf16 Bs[8192];
  const int tid = threadIdx.x, lane = tid & 63, w = tid >> 6;
  const int wm = w >> 1, wn = w & 1;
  const int m0 = blockIdx.y * 128, n0 = blockIdx.x * 128;
  const int colL = lane & 15, kg = lane >> 4;
  const int rxor = colL & 7;                 // row&7 for all fragment rows

  f32x4 acc[4][4];
  #pragma unroll
  for (int i = 0; i < 4; i++)
    #pragma unroll
    for (int j = 0; j < 4; j++) acc[i][j] = splat4(0.0f);

  for (int kb = 0; kb < K; kb += 64) {
    if (kb) __syncthreads();
    #pragma unroll
    for (int i = 0; i < 4; i++) {
      int e = (w * 4 + i) * 512 + lane * 8;
      int row = e >> 6, s = (e >> 3) & 7;
      int ksw = ((s ^ (row & 7)) << 3);      // pre-swizzled source slot
      lds_load16(&A[(size_t)(m0 + row) * K + kb + ksw], &As[(w * 4 + i) * 512]);
      lds_load16(&Bt[(size_t)(n0 + row) * K + kb + ksw], &Bs[(w * 4 + i) * 512]);
    }
    __syncthreads();
    #pragma unroll
    for (int kk = 0; kk < 2; kk++) {
      bf16x8 af[4], bfr[4];
      #pragma unroll
      for (int mt = 0; mt < 4; mt++)
        af[mt] = *(const bf16x8*)(&As[(wm * 64 + mt * 16 + colL) * 64 +
                                      (((kk * 4 + kg) ^ rxor) << 3)]);
      #pragma unroll
      for (int nt = 0; nt < 4; nt++)
        bfr[nt] = *(const bf16x8*)(&Bs[(wn * 64 + nt * 16 + colL) * 64 +
                                       (((kk * 4 + kg) ^ rxor) << 3)]);
      #pragma unroll
      for (int mt = 0; mt < 4; mt++)
        #pragma unroll
        for (int nt = 0; nt < 4; nt++)
          acc[mt][nt] = mfma16(af[mt], bfr[nt], acc[mt][nt]);
    }
  }
  #pragma unroll
  for (int mt = 0; mt < 4; mt++)
    #pragma unroll
    for (int nt = 0; nt < 4; nt++) {
      int m = m0 + wm * 64 + mt * 16 + kg * 4;
      int n = n0 + wn * 64 + nt * 16 + colL;
      #pragma unroll
      for (int r = 0; r < 4; r++)
        C[(size_t)(m + r) * Nc + n] = (bf16)acc[mt][nt][r];
    }
}

// ------------------------- cheb combine (vector) ---------------------------
// Tg[n][b][t][j] = relu(cheb_b[j] + sum_h z*Wc[0:64] + P1*Wc[64:128] + P2*Wc[128:192])
// Wave w owns j-quarter jg=w (16 channels) -> acc[16] in VGPRs, weights via s_load.
__global__ __launch_bounds__(256) void combine_kernel(const bf16* __restrict__ zf,
                                                      const bf16* __restrict__ P1f,
                                                      const bf16* __restrict__ P2f,
                                                      const float* __restrict__ Wc,
                                                      const float* __restrict__ chebb,
                                                      bf16* __restrict__ Tg) {
  const int slab = blockIdx.y;                 // bt in [0,160)
  const int b = slab / 10, t = slab % 10;
  const int lane = threadIdx.x & 63;
  const int jg = __builtin_amdgcn_readfirstlane(threadIdx.x >> 6);  // wave-uniform
  const int n = blockIdx.x * 64 + lane;

  float acc[16];
  #pragma unroll
  for (int j = 0; j < 16; j++) acc[j] = chebb[jg * 16 + j];

  const size_t zoff = (size_t)(slab * 64) * NN + n;
  #pragma unroll 1
  for (int src = 0; src < 3; src++) {
    const bf16* Z = (src == 0) ? zf : (src == 1) ? P1f : P2f;
    const float* wsrc = Wc + (size_t)(src * 64) * 64 + jg * 16;
    #pragma unroll 4
    for (int h = 0; h < 64; h++) {
      float v = (float)Z[zoff + (size_t)h * NN];
      const float* wr = wsrc + h * 64;         // uniform -> s_load
      #pragma unroll
      for (int j = 0; j < 16; j++) acc[j] += v * wr[j];
    }
  }

  bf16 tmp[16];
  #pragma unroll
  for (int j = 0; j < 16; j++) {
    float x = acc[j];
    tmp[j] = (bf16)(x > 0.0f ? x : 0.0f);
  }
  size_t base = (size_t)((n * 16 + b) * 10 + t) * 64 + jg * 16;
  *(bf16x8*)(&Tg[base])     = *(const bf16x8*)(&tmp[0]);
  *(bf16x8*)(&Tg[base + 8]) = *(const bf16x8*)(&tmp[8]);
}

// ----------------------- TC2 as GEMM + fused BN stats ----------------------
// C[131072 x 1152] = TgWin[131072 x 192] * W2c^T.
// Block: 256 rows (nodes) at fixed (b,tpp), ALL 1152 cols via cho=0..5 loop.
// 8 waves (wm=w>>1 row-slice, wn=w&1 col-half); per wave 64 rows x 96 cols/cho.
// LDS: A[256][192] (96 KB, staged once, slot-swizzled rows of 24 slots) +
//      W double-buffer 2 x [192][64] (24 KB each). 144 KB total, 1 block/CU.
// launch_bounds(512,2): 256-VGPR budget (2 waves/EU) -> no accumulator spill.
__global__ __launch_bounds__(512, 2) void tc2_kernel(const bf16* __restrict__ Tg,
                                                     const bf16* __restrict__ W2c,
                                                     const float* __restrict__ b1,
                                                     const float* __restrict__ b2,
                                                     const float* __restrict__ b3,
                                                     float* __restrict__ nsum,
                                                     float* __restrict__ nsq,
                                                     bf16* __restrict__ slice) {
  __shared__ __align__(16) char smem[147456];  // A 96K + 2 x W 24K
  bf16* Asm = (bf16*)smem;
  const int rb = blockIdx.x;                   // 512 blocks: b(16) x tpp(8) x nch(4)
  const int b = rb >> 5, tpp = (rb >> 2) & 7, n0 = (rb & 3) << 8;
  const int tid = threadIdx.x, lane = tid & 63, w = tid >> 6;
  const int wm = w >> 1, wn = w & 1;
  const int colL = lane & 15, kg = lane >> 4;
  const int rxor = colL & 7;

  // ---- stage A once: 96 KB; wave w stages bytes [w*12288, +12288)
  #pragma unroll
  for (int i = 0; i < 12; i++) {
    int fb = w * 12288 + i * 1024 + lane * 16;  // byte offset in A region
    int row = fb / 384;                          // 384 B per row (192 bf16)
    int s = (fb % 384) >> 4;                     // slot 0..23
    int koff = (s & ~7) * 8 + (((s & 7) ^ (row & 7)) << 3);
    lds_load16(&Tg[(size_t)((n0 + row) * 16 + b) * 640 + tpp * 64 + koff],
               (bf16*)(smem + w * 12288 + i * 1024));
  }
  // ---- W chunk stager: 24 KB = [192 cols][64 k], rows of 8 slots
  auto stageW = [&](int cho, int ks, int buf) {
    #pragma unroll
    for (int i = 0; i < 3; i++) {
      int fb = w * 3072 + i * 1024 + lane * 16;
      int col = fb >> 7;
      int s8 = (fb >> 4) & 7;
      lds_load16(&W2c[(size_t)(cho * 192 + col) * 192 + ks * 64 + ((s8 ^ (col & 7)) << 3)],
                 (bf16*)(smem + 98304 + buf * 24576 + w * 3072 + i * 1024));
    }
  };
  stageW(0, 0, 0);
  __syncthreads();                             // A + W0 ready

  float ssum[4][4], ssq[4][4];
  #pragma unroll
  for (int mt = 0; mt < 4; mt++)
    #pragma unroll
    for (int r = 0; r < 4; r++) { ssum[mt][r] = 0.0f; ssq[mt][r] = 0.0f; }

  #pragma unroll
  for (int cho = 0; cho < 6; cho++) {
    f32x4 acc[4][6];
    #pragma unroll
    for (int i = 0; i < 4; i++)
      #pragma unroll
      for (int j = 0; j < 6; j++) acc[i][j] = splat4(0.0f);

    #pragma unroll
    for (int ks = 0; ks < 3; ks++) {
      const int p = cho * 3 + ks;
      if (p < 17) stageW((p + 1) / 3, (p + 1) % 3, (p + 1) & 1);  // prefetch
      const bf16* Wsb = (const bf16*)(smem + 98304 + (p & 1) * 24576);
      #pragma unroll
      for (int kk = 0; kk < 2; kk++) {
        bf16x8 af[4], bfr[6];
        #pragma unroll
        for (int mt = 0; mt < 4; mt++)
          af[mt] = *(const bf16x8*)(&Asm[(wm * 64 + mt * 16 + colL) * 192 + ks * 64 +
                                         (((kk * 4 + kg) ^ rxor) << 3)]);
        #pragma unroll
        for (int j = 0; j < 6; j++)
          bfr[j] = *(const bf16x8*)(&Wsb[(wn * 96 + j * 16 + colL) * 64 +
                                         (((kk * 4 + kg) ^ rxor) << 3)]);
        #pragma unroll
        for (int mt = 0; mt < 4; mt++)
          #pragma unroll
          for (int j = 0; j < 6; j++)
            acc[mt][j] = mfma16(af[mt], bfr[j], acc[mt][j]);
      }
      __syncthreads();                         // drain prefetch + frag reads
    }

    // GLU epilogue for this cho (registers only)
    #pragma unroll
    for (int g = 0; g < 2; g++) {
      int o = ((cho * 4 + wn * 2 + g) << 4) + colL;
      float bv1 = b1[o], bv2 = b2[o], bv3 = b3[o];
      #pragma unroll
      for (int mt = 0; mt < 4; mt++)
        #pragma unroll
        for (int r = 0; r < 4; r++) {
          float p  = acc[mt][g * 3 + 0][r] + bv1;
          float q  = acc[mt][g * 3 + 1][r] + bv2;
          float rr = acc[mt][g * 3 + 2][r] + bv3;
          float h = p * (1.0f / (1.0f + __expf(-q))) + rr;
          h = h > 0.0f ? h : 0.0f;
          ssum[mt][r] += h;
          ssq[mt][r] += h * h;
          if (tpp == 7) {
            int n = n0 + wm * 64 + mt * 16 + kg * 4 + r;
            slice[(size_t)((b << 10) + n) * 384 + o] = (bf16)h;
          }
        }
    }
  }

  // reduce over colL (16 lanes) -> LDS -> 2 atomics per row (256 rows)
  float* sred = (float*)smem;                  // alias A region (done with it)
  sred[tid] = 0.0f;                            // 512 floats = [256][2]
  __syncthreads();
  #pragma unroll
  for (int mt = 0; mt < 4; mt++)
    #pragma unroll
    for (int r = 0; r < 4; r++) {
      float s = ssum[mt][r], q = ssq[mt][r];
      #pragma unroll
      for (int d = 1; d < 16; d <<= 1) {
        s += __shfl_xor(s, d);
        q += __shfl_xor(q, d);
      }
      if (colL == 0) {
        int rl = wm * 64 + mt * 16 + kg * 4 + r;   // local row [0,256)
        atomicAdd(&sred[rl * 2], s);
        atomicAdd(&sred[rl * 2 + 1], q);
      }
    }
  __syncthreads();
  if (tid < 256) {
    atomicAdd(&nsum[n0 + tid], sred[tid * 2]);
    atomicAdd(&nsq[n0 + tid], sred[tid * 2 + 1]);
  }
}

// ----------------------------- BN finalize ---------------------------------
__global__ __launch_bounds__(256) void bnstat_kernel(const float* __restrict__ nsum,
                                                     const float* __restrict__ nsq,
                                                     const float* __restrict__ gamma,
                                                     const float* __restrict__ beta,
                                                     float* __restrict__ scoff) {
  int n = blockIdx.x * 256 + threadIdx.x;       // 1024 exact
  const float inv_cnt = 1.0f / 49152.0f;        // B*8*384
  float m = nsum[n] * inv_cnt;
  float var = nsq[n] * inv_cnt - m * m;
  float sc = rsqrtf(var + 1e-5f) * gamma[n];
  scoff[n] = sc;
  scoff[1024 + n] = beta[n] - m * sc;
}

// out[f], f = c*16384 + b*1024 + n  (== reshape(T,B,N,OUT) flat order)
__global__ __launch_bounds__(256) void final_kernel(const bf16* __restrict__ slice,
                                                    const float* __restrict__ scoff,
                                                    float* __restrict__ out) {
  int f = blockIdx.x * 256 + threadIdx.x;       // 6291456 exact
  int c = f >> 14, rem = f & 16383;
  int b = rem >> 10, n = rem & 1023;
  out[f] = (float)slice[(size_t)((b << 10) + n) * 384 + c] * scoff[n] + scoff[1024 + n];
}

// ---------------------------------------------------------------------------
extern "C" void kernel_launch(void* const* d_in, const int* in_sizes, int n_in,
                              void* d_out, int out_size, void* d_ws, size_t ws_size,
                              hipStream_t stream) {
  const float* X    = (const float*)d_in[0];
  const int*   ei   = (const int*)d_in[1];
  const float* ew   = (const float*)d_in[2];
  const float* t1w1 = (const float*)d_in[3];
  const float* t1b1 = (const float*)d_in[4];
  const float* t1w2 = (const float*)d_in[5];
  const float* t1b2 = (const float*)d_in[6];
  const float* t1w3 = (const float*)d_in[7];
  const float* t1b3 = (const float*)d_in[8];
  const float* chebW = (const float*)d_in[9];
  const float* chebB = (const float*)d_in[10];
  const float* t2w1 = (const float*)d_in[11];
  const float* t2b1 = (const float*)d_in[12];
  const float* t2w2 = (const float*)d_in[13];
  const float* t2b2 = (const float*)d_in[14];
  const float* t2w3 = (const float*)d_in[15];
  const float* t2b3 = (const float*)d_in[16];
  const float* gamma = (const float*)d_in[17];
  const float* beta  = (const float*)d_in[18];
  float* out = (float*)d_out;

  char* ws = (char*)d_ws;
  float* Lf    = (float*)(ws);                  // 4 MB dense L (fp32 scatter target)
  float* deg   = (float*)(ws + 4194304);
  float* nsum  = (float*)(ws + 4198400);
  float* nsq   = (float*)(ws + 4202496);
  bf16*  Lbf   = (bf16*)(ws + 4210688);         // 2 MB
  bf16*  zf    = (bf16*)(ws + 6307840);         // 20 MB feature-major z
  bf16*  P1f   = (bf16*)(ws + 27279360);        // 20 MB
  bf16*  P2f   = (bf16*)(ws + 48250880);        // 20 MB
  bf16*  Tg    = (bf16*)(ws + 69222400);        // 20 MB node-major
  float* Wc    = (float*)(ws + 90193920);       // 48 KB combined cheb weights
  bf16*  W2c   = (bf16*)(ws + 90243072);        // 432 KB tc2 weights [col][k]
  bf16*  slice = (bf16*)(ws + 90685440);        // 12 MB t''=7 slice
  float* scoff = (float*)(ws + 103268352);      // 8 KB

  hipMemsetAsync(ws, 0, 4206592, stream);       // Lf + deg + nsum + nsq

  wprep_kernel<<<912, 256, 0, stream>>>(chebW, t2w1, t2w2, t2w3, Wc, W2c);
  tc1_kernel<<<dim3(4, 10240), 256, 0, stream>>>(X, t1w1, t1b1, t1w2, t1b2, t1w3, t1b3, zf);
  deg_kernel<<<64, 256, 0, stream>>>(ei, ew, deg);
  scatterL_kernel<<<64, 256, 0, stream>>>(ei, ew, deg, Lf);
  cvtL_kernel<<<4096, 256, 0, stream>>>(Lf, Lbf);
  gemm_bt<<<dim3(8, 80), 256, 0, stream>>>(zf, Lbf, P1f, 10240, 1024, 1024);
  gemm_bt<<<dim3(8, 80), 256, 0, stream>>>(P1f, Lbf, P2f, 10240, 1024, 1024);
  combine_kernel<<<dim3(16, 160), 256, 0, stream>>>(zf, P1f, P2f, Wc, chebB, Tg);
  tc2_kernel<<<512, 512, 0, stream>>>(Tg, W2c, t2b1, t2b2, t2b3, nsum, nsq, slice);
  bnstat_kernel<<<4, 256, 0, stream>>>(nsum, nsq, gamma, beta, scoff);
  final_kernel<<<24576, 256, 0, stream>>>(slice, scoff, out);
}

// Round 9
// 464.110 us; speedup vs baseline: 1.0527x; 1.0375x over previous
//
#include <hip/hip_runtime.h>

// ---------------------------------------------------------------------------
// STGCN forward, MI355X. Internal compute bf16-MFMA / fp32-accum.
// TC1 -> (dense-L build) -> prop GEMM x2 -> cheb combine -> TC2-as-GEMM+stats
// -> BN finalize. T2 never materialized (only per-node stats + t''=7 slice).
// LDS tiles use XOR slot-swizzle (pre-swizzled global source, swizzled read).
// tc2 v4: A[256][192] LDS-resident (96 KB, staged once); W in 12 KB
// half-chunks [96][64], double-buffered, prefetched 1 phase ahead (36 phases).
// Live acc = [4][3] (48 VGPR) -> fits the 128-VGPR budget, no spill (R6/R7's
// 460 MB scratch traffic was acc[4][6]=96-VGPR spill at 128 budget).
// ---------------------------------------------------------------------------

typedef __bf16 bf16;
typedef __bf16 bf16x8 __attribute__((ext_vector_type(8)));
typedef float  f32x4  __attribute__((ext_vector_type(4)));

__device__ __forceinline__ f32x4 mfma16(bf16x8 a, bf16x8 b, f32x4 c) {
  return __builtin_amdgcn_mfma_f32_16x16x32_bf16(a, b, c, 0, 0, 0);
}
__device__ __forceinline__ f32x4 splat4(float v) { f32x4 t = {v, v, v, v}; return t; }

// async global->LDS, 16B per lane; lds base must be wave-uniform (lane*16 auto)
__device__ __forceinline__ void lds_load16(const bf16* g, bf16* l) {
  __builtin_amdgcn_global_load_lds((const __attribute__((address_space(1))) void*)g,
                                   (__attribute__((address_space(3))) void*)l, 16, 0, 0);
}

#define NN 1024
#define EE 16384

// --------------------------- edge preprocessing ----------------------------
__global__ __launch_bounds__(256) void deg_kernel(const int* __restrict__ ei,
                                                  const float* __restrict__ ew,
                                                  float* __restrict__ deg) {
  int e = blockIdx.x * 256 + threadIdx.x;
  int r = ei[e], c = ei[EE + e];
  if (r != c) atomicAdd(&deg[r], ew[e]);
}

// L[col][row] += -dinv[row]*w*dinv[col]  (dense 1024x1024 fp32)
__global__ __launch_bounds__(256) void scatterL_kernel(const int* __restrict__ ei,
                                                       const float* __restrict__ ew,
                                                       const float* __restrict__ deg,
                                                       float* __restrict__ Lf) {
  int e = blockIdx.x * 256 + threadIdx.x;
  int r = ei[e], c = ei[EE + e];
  float w = (r == c) ? 0.0f : ew[e];
  float dr = deg[r], dc = deg[c];
  float ir = dr > 0.0f ? rsqrtf(dr) : 0.0f;
  float ic = dc > 0.0f ? rsqrtf(dc) : 0.0f;
  float norm = -(ir * w * ic);
  if (norm != 0.0f) atomicAdd(&Lf[(size_t)c * NN + r], norm);
}

__global__ __launch_bounds__(256) void cvtL_kernel(const float* __restrict__ Lf,
                                                   bf16* __restrict__ Lbf) {
  int i = blockIdx.x * 256 + threadIdx.x;
  Lbf[i] = (bf16)Lf[i];
}

// ------------------------------ weight prep --------------------------------
// Wc (fp32, 192x64): rows [0:64)=W0-W2, [64:128)=W1, [128:192)=2*W2
// W2c (bf16, [1152 cols][192 k]): col = og*48 + conv*16 + oo  (o = og*16+oo)
//   k = kk*64 + h ; value = w_conv[(o*64+h)*3 + kk]
__global__ __launch_bounds__(256) void wprep_kernel(const float* __restrict__ W,
                                                    const float* __restrict__ w21,
                                                    const float* __restrict__ w22,
                                                    const float* __restrict__ w23,
                                                    float* __restrict__ Wc,
                                                    bf16* __restrict__ W2c) {
  int i = blockIdx.x * 256 + threadIdx.x;   // 912*256 = 233472 = 12288 + 221184 exact
  if (i < 12288) {
    int row = i >> 6, j = i & 63;
    int src = row >> 6, h = row & 63;
    float v;
    if (src == 0)      v = W[h * 64 + j] - W[2 * 4096 + h * 64 + j];
    else if (src == 1) v = W[4096 + h * 64 + j];
    else               v = 2.0f * W[2 * 4096 + h * 64 + j];
    Wc[i] = v;
  } else {
    int j2 = i - 12288;                      // [0, 221184)
    int c = j2 / 192, k = j2 % 192;
    int og = c / 48, r48 = c % 48;
    int conv = r48 >> 4, oo = r48 & 15;
    int o = og * 16 + oo;
    int kk = k >> 6, h = k & 63;
    const float* ws = (conv == 0) ? w21 : (conv == 1) ? w22 : w23;
    W2c[j2] = (bf16)ws[(o * 64 + h) * 3 + kk];
  }
}

// ------------------------------- TC1 ---------------------------------------
// zf[(b*10+t)*64+h][n] = relu(P*sigmoid(Q)+R), feature-major bf16
__global__ __launch_bounds__(256) void tc1_kernel(const float* __restrict__ X,
                                                  const float* __restrict__ w1, const float* __restrict__ c1,
                                                  const float* __restrict__ w2, const float* __restrict__ c2,
                                                  const float* __restrict__ w3, const float* __restrict__ c3,
                                                  bf16* __restrict__ zf) {
  int row = blockIdx.y;                       // (b*10+t)*64+h, [0,10240)
  int n = blockIdx.x * 256 + threadIdx.x;
  int h = row & 63, bt = row >> 6;
  int t = bt % 10, b = bt / 10;
  float P = c1[h], Q = c2[h], R = c3[h];
  const float* xb = X + (size_t)(b * 1024 + n) * 24;   // (B,N,C=2,T=12)
  #pragma unroll
  for (int c = 0; c < 2; c++)
    #pragma unroll
    for (int k = 0; k < 3; k++) {
      float xv = xb[c * 12 + t + k];
      int wi = (h * 2 + c) * 3 + k;
      P += xv * w1[wi]; Q += xv * w2[wi]; R += xv * w3[wi];
    }
  float Hv = P * (1.0f / (1.0f + __expf(-Q))) + R;
  Hv = Hv > 0.0f ? Hv : 0.0f;
  zf[(size_t)row * NN + n] = (bf16)Hv;
}

// --------------------------- B^T GEMM (bf16) -------------------------------
// C[M][Nc] = A[M][K] * Bt[Nc][K]^T ; 128x128 tile, BK=64, global_load_lds.
// LDS rows of 64 bf16 = 8 slots of 16B; physical slot = logical ^ (row&7).
__global__ __launch_bounds__(256) void gemm_bt(const bf16* __restrict__ A,
                                               const bf16* __restrict__ Bt,
                                               bf16* __restrict__ C,
                                               int M, int Nc, int K) {
  __shared__ __align__(16) bf16 As[8192];
  __shared__ __align__(16) bf16 Bs[8192];
  const int tid = threadIdx.x, lane = tid & 63, w = tid >> 6;
  const int wm = w >> 1, wn = w & 1;
  const int m0 = blockIdx.y * 128, n0 = blockIdx.x * 128;
  const int colL = lane & 15, kg = lane >> 4;
  const int rxor = colL & 7;                 // row&7 for all fragment rows

  f32x4 acc[4][4];
  #pragma unroll
  for (int i = 0; i < 4; i++)
    #pragma unroll
    for (int j = 0; j < 4; j++) acc[i][j] = splat4(0.0f);

  for (int kb = 0; kb < K; kb += 64) {
    if (kb) __syncthreads();
    #pragma unroll
    for (int i = 0; i < 4; i++) {
      int e = (w * 4 + i) * 512 + lane * 8;
      int row = e >> 6, s = (e >> 3) & 7;
      int ksw = ((s ^ (row & 7)) << 3);      // pre-swizzled source slot
      lds_load16(&A[(size_t)(m0 + row) * K + kb + ksw], &As[(w * 4 + i) * 512]);
      lds_load16(&Bt[(size_t)(n0 + row) * K + kb + ksw], &Bs[(w * 4 + i) * 512]);
    }
    __syncthreads();
    #pragma unroll
    for (int kk = 0; kk < 2; kk++) {
      bf16x8 af[4], bfr[4];
      #pragma unroll
      for (int mt = 0; mt < 4; mt++)
        af[mt] = *(const bf16x8*)(&As[(wm * 64 + mt * 16 + colL) * 64 +
                                      (((kk * 4 + kg) ^ rxor) << 3)]);
      #pragma unroll
      for (int nt = 0; nt < 4; nt++)
        bfr[nt] = *(const bf16x8*)(&Bs[(wn * 64 + nt * 16 + colL) * 64 +
                                       (((kk * 4 + kg) ^ rxor) << 3)]);
      #pragma unroll
      for (int mt = 0; mt < 4; mt++)
        #pragma unroll
        for (int nt = 0; nt < 4; nt++)
          acc[mt][nt] = mfma16(af[mt], bfr[nt], acc[mt][nt]);
    }
  }
  #pragma unroll
  for (int mt = 0; mt < 4; mt++)
    #pragma unroll
    for (int nt = 0; nt < 4; nt++) {
      int m = m0 + wm * 64 + mt * 16 + kg * 4;
      int n = n0 + wn * 64 + nt * 16 + colL;
      #pragma unroll
      for (int r = 0; r < 4; r++)
        C[(size_t)(m + r) * Nc + n] = (bf16)acc[mt][nt][r];
    }
}

// ------------------------- cheb combine (vector) ---------------------------
// Tg[n][b][t][j] = relu(cheb_b[j] + sum_h z*Wc[0:64] + P1*Wc[64:128] + P2*Wc[128:192])
// Wave w owns j-quarter jg=w (16 channels) -> acc[16] in VGPRs, weights via s_load.
__global__ __launch_bounds__(256) void combine_kernel(const bf16* __restrict__ zf,
                                                      const bf16* __restrict__ P1f,
                                                      const bf16* __restrict__ P2f,
                                                      const float* __restrict__ Wc,
                                                      const float* __restrict__ chebb,
                                                      bf16* __restrict__ Tg) {
  const int slab = blockIdx.y;                 // bt in [0,160)
  const int b = slab / 10, t = slab % 10;
  const int lane = threadIdx.x & 63;
  const int jg = __builtin_amdgcn_readfirstlane(threadIdx.x >> 6);  // wave-uniform
  const int n = blockIdx.x * 64 + lane;

  float acc[16];
  #pragma unroll
  for (int j = 0; j < 16; j++) acc[j] = chebb[jg * 16 + j];

  const size_t zoff = (size_t)(slab * 64) * NN + n;
  #pragma unroll 1
  for (int src = 0; src < 3; src++) {
    const bf16* Z = (src == 0) ? zf : (src == 1) ? P1f : P2f;
    const float* wsrc = Wc + (size_t)(src * 64) * 64 + jg * 16;
    #pragma unroll 4
    for (int h = 0; h < 64; h++) {
      float v = (float)Z[zoff + (size_t)h * NN];
      const float* wr = wsrc + h * 64;         // uniform -> s_load
      #pragma unroll
      for (int j = 0; j < 16; j++) acc[j] += v * wr[j];
    }
  }

  bf16 tmp[16];
  #pragma unroll
  for (int j = 0; j < 16; j++) {
    float x = acc[j];
    tmp[j] = (bf16)(x > 0.0f ? x : 0.0f);
  }
  size_t base = (size_t)((n * 16 + b) * 10 + t) * 64 + jg * 16;
  *(bf16x8*)(&Tg[base])     = *(const bf16x8*)(&tmp[0]);
  *(bf16x8*)(&Tg[base + 8]) = *(const bf16x8*)(&tmp[8]);
}

// ----------------------- TC2 as GEMM + fused BN stats ----------------------
// C[131072 x 1152] = TgWin[131072 x 192] * W2c^T.
// Block: 256 rows (b,tpp,n-chunk), all 1152 cols via 12 (cho,half) passes.
// 8 waves: wm=w>>1 -> 64-row slice; wn=w&1 -> 48-col slice of the 96-col half.
// Per (cho,half): wave owns ONE o-group og=cho*4+half*2+wn with its 3 convs
// (GLU triple lane-local). acc[4][3] = 48 VGPR (fits 128 budget; R6/R7's
// acc[4][6]=96 spilled 460 MB to scratch).
// LDS: A[256][192] 96 KB staged once + W half-chunks 2 x 12 KB dbuf = 120 KB.
// 36 phases, chunk p+1 prefetched during compute of p.
__global__ __launch_bounds__(512, 2) void tc2_kernel(const bf16* __restrict__ Tg,
                                                     const bf16* __restrict__ W2c,
                                                     const float* __restrict__ b1,
                                                     const float* __restrict__ b2,
                                                     const float* __restrict__ b3,
                                                     float* __restrict__ nsum,
                                                     float* __restrict__ nsq,
                                                     bf16* __restrict__ slice) {
  __shared__ __align__(16) char smem[122880];  // A 96K + 2 x W 12K
  bf16* Asm = (bf16*)smem;
  const int rb = blockIdx.x;                   // 512 blocks: b(16) x tpp(8) x nch(4)
  const int b = rb >> 5, tpp = (rb >> 2) & 7, n0 = (rb & 3) << 8;
  const int tid = threadIdx.x, lane = tid & 63, w = tid >> 6;
  const int wm = w >> 1, wn = w & 1;
  const int colL = lane & 15, kg = lane >> 4;
  const int rxor = colL & 7;

  // ---- stage A once: 96 KB; wave w stages bytes [w*12288, +12288)
  #pragma unroll
  for (int i = 0; i < 12; i++) {
    int fb = w * 12288 + i * 1024 + lane * 16;  // byte offset in A region
    int row = fb / 384;                          // 384 B per row (192 bf16)
    int s = (fb % 384) >> 4;                     // slot 0..23
    int koff = (s & ~7) * 8 + (((s & 7) ^ (row & 7)) << 3);
    lds_load16(&Tg[(size_t)((n0 + row) * 16 + b) * 640 + tpp * 64 + koff],
               (bf16*)(smem + w * 12288 + i * 1024));
  }
  // ---- W half-chunk stager: 12 KB = [96 cols][64 k], rows of 8 slots.
  // 12 x 1024B segments; wave w takes seg w (+ seg w+8 for w<4).
  auto stageW = [&](int cho, int half, int ks, int buf) {
    {
      int lc = w * 8 + (lane >> 3);
      int cg = cho * 192 + half * 96 + lc;
      int ksrc = ks * 64 + (((lane & 7) ^ (cg & 7)) << 3);
      lds_load16(&W2c[(size_t)cg * 192 + ksrc],
                 (bf16*)(smem + 98304 + buf * 12288 + w * 1024));
    }
    if (w < 4) {
      int s2 = w + 8;
      int lc = s2 * 8 + (lane >> 3);
      int cg = cho * 192 + half * 96 + lc;
      int ksrc = ks * 64 + (((lane & 7) ^ (cg & 7)) << 3);
      lds_load16(&W2c[(size_t)cg * 192 + ksrc],
                 (bf16*)(smem + 98304 + buf * 12288 + s2 * 1024));
    }
  };
  stageW(0, 0, 0, 0);
  __syncthreads();                             // A + chunk0 ready

  float ssum[4][4], ssq[4][4];
  #pragma unroll
  for (int mt = 0; mt < 4; mt++)
    #pragma unroll
    for (int r = 0; r < 4; r++) { ssum[mt][r] = 0.0f; ssq[mt][r] = 0.0f; }

  #pragma unroll
  for (int cho = 0; cho < 6; cho++) {
    #pragma unroll
    for (int half = 0; half < 2; half++) {
      f32x4 acc[4][3];
      #pragma unroll
      for (int i = 0; i < 4; i++)
        #pragma unroll
        for (int j = 0; j < 3; j++) acc[i][j] = splat4(0.0f);

      #pragma unroll
      for (int ks = 0; ks < 3; ks++) {
        const int p = (cho * 2 + half) * 3 + ks;
        if (p < 35) {
          const int q = p + 1;
          stageW(q / 6, (q % 6) / 3, q % 3, q & 1);   // prefetch next chunk
        }
        const bf16* Wsb = (const bf16*)(smem + 98304 + (p & 1) * 12288);
        #pragma unroll
        for (int kk = 0; kk < 2; kk++) {
          bf16x8 af[4], bfr[3];
          #pragma unroll
          for (int mt = 0; mt < 4; mt++)
            af[mt] = *(const bf16x8*)(&Asm[(wm * 64 + mt * 16 + colL) * 192 + ks * 64 +
                                           (((kk * 4 + kg) ^ rxor) << 3)]);
          #pragma unroll
          for (int j = 0; j < 3; j++)
            bfr[j] = *(const bf16x8*)(&Wsb[(wn * 48 + j * 16 + colL) * 64 +
                                           (((kk * 4 + kg) ^ rxor) << 3)]);
          #pragma unroll
          for (int mt = 0; mt < 4; mt++)
            #pragma unroll
            for (int j = 0; j < 3; j++)
              acc[mt][j] = mfma16(af[mt], bfr[j], acc[mt][j]);
        }
        __syncthreads();                       // chunk p+1 arrived; bufs free
      }

      // GLU epilogue for this (cho,half): one og per wave, convs = j 0..2
      const int o = ((cho * 4 + half * 2 + wn) << 4) + colL;
      const float bv1 = b1[o], bv2 = b2[o], bv3 = b3[o];
      #pragma unroll
      for (int mt = 0; mt < 4; mt++)
        #pragma unroll
        for (int r = 0; r < 4; r++) {
          float pv = acc[mt][0][r] + bv1;
          float qv = acc[mt][1][r] + bv2;
          float rv = acc[mt][2][r] + bv3;
          float h = pv * (1.0f / (1.0f + __expf(-qv))) + rv;
          h = h > 0.0f ? h : 0.0f;
          ssum[mt][r] += h;
          ssq[mt][r] += h * h;
          if (tpp == 7) {
            int n = n0 + wm * 64 + mt * 16 + kg * 4 + r;
            slice[(size_t)((b << 10) + n) * 384 + o] = (bf16)h;
          }
        }
    }
  }

  // reduce over colL (16 lanes) -> LDS -> 2 atomics per row (256 rows)
  float* sred = (float*)smem;                  // alias A region (done with it)
  sred[tid] = 0.0f;                            // 512 floats = [256][2]
  __syncthreads();
  #pragma unroll
  for (int mt = 0; mt < 4; mt++)
    #pragma unroll
    for (int r = 0; r < 4; r++) {
      float s = ssum[mt][r], q = ssq[mt][r];
      #pragma unroll
      for (int d = 1; d < 16; d <<= 1) {
        s += __shfl_xor(s, d);
        q += __shfl_xor(q, d);
      }
      if (colL == 0) {
        int rl = wm * 64 + mt * 16 + kg * 4 + r;   // local row [0,256)
        atomicAdd(&sred[rl * 2], s);
        atomicAdd(&sred[rl * 2 + 1], q);
      }
    }
  __syncthreads();
  if (tid < 256) {
    atomicAdd(&nsum[n0 + tid], sred[tid * 2]);
    atomicAdd(&nsq[n0 + tid], sred[tid * 2 + 1]);
  }
}

// ----------------------------- BN finalize ---------------------------------
__global__ __launch_bounds__(256) void bnstat_kernel(const float* __restrict__ nsum,
                                                     const float* __restrict__ nsq,
                                                     const float* __restrict__ gamma,
                                                     const float* __restrict__ beta,
                                                     float* __restrict__ scoff) {
  int n = blockIdx.x * 256 + threadIdx.x;       // 1024 exact
  const float inv_cnt = 1.0f / 49152.0f;        // B*8*384
  float m = nsum[n] * inv_cnt;
  float var = nsq[n] * inv_cnt - m * m;
  float sc = rsqrtf(var + 1e-5f) * gamma[n];
  scoff[n] = sc;
  scoff[1024 + n] = beta[n] - m * sc;
}

// out[f], f = c*16384 + b*1024 + n  (== reshape(T,B,N,OUT) flat order)
__global__ __launch_bounds__(256) void final_kernel(const bf16* __restrict__ slice,
                                                    const float* __restrict__ scoff,
                                                    float* __restrict__ out) {
  int f = blockIdx.x * 256 + threadIdx.x;       // 6291456 exact
  int c = f >> 14, rem = f & 16383;
  int b = rem >> 10, n = rem & 1023;
  out[f] = (float)slice[(size_t)((b << 10) + n) * 384 + c] * scoff[n] + scoff[1024 + n];
}

// ---------------------------------------------------------------------------
extern "C" void kernel_launch(void* const* d_in, const int* in_sizes, int n_in,
                              void* d_out, int out_size, void* d_ws, size_t ws_size,
                              hipStream_t stream) {
  const float* X    = (const float*)d_in[0];
  const int*   ei   = (const int*)d_in[1];
  const float* ew   = (const float*)d_in[2];
  const float* t1w1 = (const float*)d_in[3];
  const float* t1b1 = (const float*)d_in[4];
  const float* t1w2 = (const float*)d_in[5];
  const float* t1b2 = (const float*)d_in[6];
  const float* t1w3 = (const float*)d_in[7];
  const float* t1b3 = (const float*)d_in[8];
  const float* chebW = (const float*)d_in[9];
  const float* chebB = (const float*)d_in[10];
  const float* t2w1 = (const float*)d_in[11];
  const float* t2b1 = (const float*)d_in[12];
  const float* t2w2 = (const float*)d_in[13];
  const float* t2b2 = (const float*)d_in[14];
  const float* t2w3 = (const float*)d_in[15];
  const float* t2b3 = (const float*)d_in[16];
  const float* gamma = (const float*)d_in[17];
  const float* beta  = (const float*)d_in[18];
  float* out = (float*)d_out;

  char* ws = (char*)d_ws;
  float* Lf    = (float*)(ws);                  // 4 MB dense L (fp32 scatter target)
  float* deg   = (float*)(ws + 4194304);
  float* nsum  = (float*)(ws + 4198400);
  float* nsq   = (float*)(ws + 4202496);
  bf16*  Lbf   = (bf16*)(ws + 4210688);         // 2 MB
  bf16*  zf    = (bf16*)(ws + 6307840);         // 20 MB feature-major z
  bf16*  P1f   = (bf16*)(ws + 27279360);        // 20 MB
  bf16*  P2f   = (bf16*)(ws + 48250880);        // 20 MB
  bf16*  Tg    = (bf16*)(ws + 69222400);        // 20 MB node-major
  float* Wc    = (float*)(ws + 90193920);       // 48 KB combined cheb weights
  bf16*  W2c   = (bf16*)(ws + 90243072);        // 432 KB tc2 weights [col][k]
  bf16*  slice = (bf16*)(ws + 90685440);        // 12 MB t''=7 slice
  float* scoff = (float*)(ws + 103268352);      // 8 KB

  hipMemsetAsync(ws, 0, 4206592, stream);       // Lf + deg + nsum + nsq

  wprep_kernel<<<912, 256, 0, stream>>>(chebW, t2w1, t2w2, t2w3, Wc, W2c);
  tc1_kernel<<<dim3(4, 10240), 256, 0, stream>>>(X, t1w1, t1b1, t1w2, t1b2, t1w3, t1b3, zf);
  deg_kernel<<<64, 256, 0, stream>>>(ei, ew, deg);
  scatterL_kernel<<<64, 256, 0, stream>>>(ei, ew, deg, Lf);
  cvtL_kernel<<<4096, 256, 0, stream>>>(Lf, Lbf);
  gemm_bt<<<dim3(8, 80), 256, 0, stream>>>(zf, Lbf, P1f, 10240, 1024, 1024);
  gemm_bt<<<dim3(8, 80), 256, 0, stream>>>(P1f, Lbf, P2f, 10240, 1024, 1024);
  combine_kernel<<<dim3(16, 160), 256, 0, stream>>>(zf, P1f, P2f, Wc, chebB, Tg);
  tc2_kernel<<<512, 512, 0, stream>>>(Tg, W2c, t2b1, t2b2, t2b3, nsum, nsq, slice);
  bnstat_kernel<<<4, 256, 0, stream>>>(nsum, nsq, gamma, beta, scoff);
  final_kernel<<<24576, 256, 0, stream>>>(slice, scoff, out);
}

// Round 11
// 365.591 us; speedup vs baseline: 1.3364x; 1.2695x over previous
//
#include <hip/hip_runtime.h>

// ---------------------------------------------------------------------------
// STGCN forward, MI355X. Internal compute bf16-MFMA / fp32-accum.
// TC1 -> (dense-L build) -> prop GEMM x2 -> cheb combine -> TC2-as-GEMM+stats
// -> BN finalize. T2 never materialized (only per-node stats + t''=7 slice).
// LDS tiles use XOR slot-swizzle (pre-swizzled global source, swizzled read).
// tc2 v5: A[256][192] LDS-resident (96 KB, staged once); W in 12 KB chunks
// [96 cols][64 k], double-buffered, prefetched 1 chunk ahead. The 12-pass
// column loop is a RUNTIME loop (#pragma unroll 1): per-iteration live set
// acc[4][3]+stats+frags ~120 VGPR fits the 128 budget -> no spill (R6-R8's
// full unroll inflated live ranges -> 350-460 MB scratch traffic).
// ---------------------------------------------------------------------------

typedef __bf16 bf16;
typedef __bf16 bf16x8 __attribute__((ext_vector_type(8)));
typedef float  f32x4  __attribute__((ext_vector_type(4)));

__device__ __forceinline__ f32x4 mfma16(bf16x8 a, bf16x8 b, f32x4 c) {
  return __builtin_amdgcn_mfma_f32_16x16x32_bf16(a, b, c, 0, 0, 0);
}
__device__ __forceinline__ f32x4 splat4(float v) { f32x4 t = {v, v, v, v}; return t; }

// async global->LDS, 16B per lane; lds base must be wave-uniform (lane*16 auto)
__device__ __forceinline__ void lds_load16(const bf16* g, bf16* l) {
  __builtin_amdgcn_global_load_lds((const __attribute__((address_space(1))) void*)g,
                                   (__attribute__((address_space(3))) void*)l, 16, 0, 0);
}

#define NN 1024
#define EE 16384

// --------------------------- edge preprocessing ----------------------------
__global__ __launch_bounds__(256) void deg_kernel(const int* __restrict__ ei,
                                                  const float* __restrict__ ew,
                                                  float* __restrict__ deg) {
  int e = blockIdx.x * 256 + threadIdx.x;
  int r = ei[e], c = ei[EE + e];
  if (r != c) atomicAdd(&deg[r], ew[e]);
}

// L[col][row] += -dinv[row]*w*dinv[col]  (dense 1024x1024 fp32)
__global__ __launch_bounds__(256) void scatterL_kernel(const int* __restrict__ ei,
                                                       const float* __restrict__ ew,
                                                       const float* __restrict__ deg,
                                                       float* __restrict__ Lf) {
  int e = blockIdx.x * 256 + threadIdx.x;
  int r = ei[e], c = ei[EE + e];
  float w = (r == c) ? 0.0f : ew[e];
  float dr = deg[r], dc = deg[c];
  float ir = dr > 0.0f ? rsqrtf(dr) : 0.0f;
  float ic = dc > 0.0f ? rsqrtf(dc) : 0.0f;
  float norm = -(ir * w * ic);
  if (norm != 0.0f) atomicAdd(&Lf[(size_t)c * NN + r], norm);
}

__global__ __launch_bounds__(256) void cvtL_kernel(const float* __restrict__ Lf,
                                                   bf16* __restrict__ Lbf) {
  int i = blockIdx.x * 256 + threadIdx.x;
  Lbf[i] = (bf16)Lf[i];
}

// ------------------------------ weight prep --------------------------------
// Wc (fp32, 192x64): rows [0:64)=W0-W2, [64:128)=W1, [128:192)=2*W2
// W2c (bf16, [1152 cols][192 k]): col = og*48 + conv*16 + oo  (o = og*16+oo)
//   k = kk*64 + h ; value = w_conv[(o*64+h)*3 + kk]
__global__ __launch_bounds__(256) void wprep_kernel(const float* __restrict__ W,
                                                    const float* __restrict__ w21,
                                                    const float* __restrict__ w22,
                                                    const float* __restrict__ w23,
                                                    float* __restrict__ Wc,
                                                    bf16* __restrict__ W2c) {
  int i = blockIdx.x * 256 + threadIdx.x;   // 912*256 = 233472 = 12288 + 221184 exact
  if (i < 12288) {
    int row = i >> 6, j = i & 63;
    int src = row >> 6, h = row & 63;
    float v;
    if (src == 0)      v = W[h * 64 + j] - W[2 * 4096 + h * 64 + j];
    else if (src == 1) v = W[4096 + h * 64 + j];
    else               v = 2.0f * W[2 * 4096 + h * 64 + j];
    Wc[i] = v;
  } else {
    int j2 = i - 12288;                      // [0, 221184)
    int c = j2 / 192, k = j2 % 192;
    int og = c / 48, r48 = c % 48;
    int conv = r48 >> 4, oo = r48 & 15;
    int o = og * 16 + oo;
    int kk = k >> 6, h = k & 63;
    const float* ws = (conv == 0) ? w21 : (conv == 1) ? w22 : w23;
    W2c[j2] = (bf16)ws[(o * 64 + h) * 3 + kk];
  }
}

// ------------------------------- TC1 ---------------------------------------
// zf[(b*10+t)*64+h][n] = relu(P*sigmoid(Q)+R), feature-major bf16
__global__ __launch_bounds__(256) void tc1_kernel(const float* __restrict__ X,
                                                  const float* __restrict__ w1, const float* __restrict__ c1,
                                                  const float* __restrict__ w2, const float* __restrict__ c2,
                                                  const float* __restrict__ w3, const float* __restrict__ c3,
                                                  bf16* __restrict__ zf) {
  int row = blockIdx.y;                       // (b*10+t)*64+h, [0,10240)
  int n = blockIdx.x * 256 + threadIdx.x;
  int h = row & 63, bt = row >> 6;
  int t = bt % 10, b = bt / 10;
  float P = c1[h], Q = c2[h], R = c3[h];
  const float* xb = X + (size_t)(b * 1024 + n) * 24;   // (B,N,C=2,T=12)
  #pragma unroll
  for (int c = 0; c < 2; c++)
    #pragma unroll
    for (int k = 0; k < 3; k++) {
      float xv = xb[c * 12 + t + k];
      int wi = (h * 2 + c) * 3 + k;
      P += xv * w1[wi]; Q += xv * w2[wi]; R += xv * w3[wi];
    }
  float Hv = P * (1.0f / (1.0f + __expf(-Q))) + R;
  Hv = Hv > 0.0f ? Hv : 0.0f;
  zf[(size_t)row * NN + n] = (bf16)Hv;
}

// --------------------------- B^T GEMM (bf16) -------------------------------
// C[M][Nc] = A[M][K] * Bt[Nc][K]^T ; 128x128 tile, BK=64, global_load_lds.
// LDS rows of 64 bf16 = 8 slots of 16B; physical slot = logical ^ (row&7).
__global__ __launch_bounds__(256) void gemm_bt(const bf16* __restrict__ A,
                                               const bf16* __restrict__ Bt,
                                               bf16* __restrict__ C,
                                               int M, int Nc, int K) {
  __shared__ __align__(16) bf16 As[8192];
  __shared__ __align__(16) bf16 Bs[8192];
  const int tid = threadIdx.x, lane = tid & 63, w = tid >> 6;
  const int wm = w >> 1, wn = w & 1;
  const int m0 = blockIdx.y * 128, n0 = blockIdx.x * 128;
  const int colL = lane & 15, kg = lane >> 4;
  const int rxor = colL & 7;                 // row&7 for all fragment rows

  f32x4 acc[4][4];
  #pragma unroll
  for (int i = 0; i < 4; i++)
    #pragma unroll
    for (int j = 0; j < 4; j++) acc[i][j] = splat4(0.0f);

  for (int kb = 0; kb < K; kb += 64) {
    if (kb) __syncthreads();
    #pragma unroll
    for (int i = 0; i < 4; i++) {
      int e = (w * 4 + i) * 512 + lane * 8;
      int row = e >> 6, s = (e >> 3) & 7;
      int ksw = ((s ^ (row & 7)) << 3);      // pre-swizzled source slot
      lds_load16(&A[(size_t)(m0 + row) * K + kb + ksw], &As[(w * 4 + i) * 512]);
      lds_load16(&Bt[(size_t)(n0 + row) * K + kb + ksw], &Bs[(w * 4 + i) * 512]);
    }
    __syncthreads();
    #pragma unroll
    for (int kk = 0; kk < 2; kk++) {
      bf16x8 af[4], bfr[4];
      #pragma unroll
      for (int mt = 0; mt < 4; mt++)
        af[mt] = *(const bf16x8*)(&As[(wm * 64 + mt * 16 + colL) * 64 +
                                      (((kk * 4 + kg) ^ rxor) << 3)]);
      #pragma unroll
      for (int nt = 0; nt < 4; nt++)
        bfr[nt] = *(const bf16x8*)(&Bs[(wn * 64 + nt * 16 + colL) * 64 +
                                       (((kk * 4 + kg) ^ rxor) << 3)]);
      #pragma unroll
      for (int mt = 0; mt < 4; mt++)
        #pragma unroll
        for (int nt = 0; nt < 4; nt++)
          acc[mt][nt] = mfma16(af[mt], bfr[nt], acc[mt][nt]);
    }
  }
  #pragma unroll
  for (int mt = 0; mt < 4; mt++)
    #pragma unroll
    for (int nt = 0; nt < 4; nt++) {
      int m = m0 + wm * 64 + mt * 16 + kg * 4;
      int n = n0 + wn * 64 + nt * 16 + colL;
      #pragma unroll
      for (int r = 0; r < 4; r++)
        C[(size_t)(m + r) * Nc + n] = (bf16)acc[mt][nt][r];
    }
}

// ------------------------- cheb combine (vector) ---------------------------
// Tg[n][b][t][j] = relu(cheb_b[j] + sum_h z*Wc[0:64] + P1*Wc[64:128] + P2*Wc[128:192])
// Wave w owns j-quarter jg=w (16 channels) -> acc[16] in VGPRs, weights via s_load.
__global__ __launch_bounds__(256) void combine_kernel(const bf16* __restrict__ zf,
                                                      const bf16* __restrict__ P1f,
                                                      const bf16* __restrict__ P2f,
                                                      const float* __restrict__ Wc,
                                                      const float* __restrict__ chebb,
                                                      bf16* __restrict__ Tg) {
  const int slab = blockIdx.y;                 // bt in [0,160)
  const int b = slab / 10, t = slab % 10;
  const int lane = threadIdx.x & 63;
  const int jg = __builtin_amdgcn_readfirstlane(threadIdx.x >> 6);  // wave-uniform
  const int n = blockIdx.x * 64 + lane;

  float acc[16];
  #pragma unroll
  for (int j = 0; j < 16; j++) acc[j] = chebb[jg * 16 + j];

  const size_t zoff = (size_t)(slab * 64) * NN + n;
  #pragma unroll 1
  for (int src = 0; src < 3; src++) {
    const bf16* Z = (src == 0) ? zf : (src == 1) ? P1f : P2f;
    const float* wsrc = Wc + (size_t)(src * 64) * 64 + jg * 16;
    #pragma unroll 4
    for (int h = 0; h < 64; h++) {
      float v = (float)Z[zoff + (size_t)h * NN];
      const float* wr = wsrc + h * 64;         // uniform -> s_load
      #pragma unroll
      for (int j = 0; j < 16; j++) acc[j] += v * wr[j];
    }
  }

  bf16 tmp[16];
  #pragma unroll
  for (int j = 0; j < 16; j++) {
    float x = acc[j];
    tmp[j] = (bf16)(x > 0.0f ? x : 0.0f);
  }
  size_t base = (size_t)((n * 16 + b) * 10 + t) * 64 + jg * 16;
  *(bf16x8*)(&Tg[base])     = *(const bf16x8*)(&tmp[0]);
  *(bf16x8*)(&Tg[base + 8]) = *(const bf16x8*)(&tmp[8]);
}

// ----------------------- TC2 as GEMM + fused BN stats ----------------------
// C[131072 x 1152] = TgWin[131072 x 192] * W2c^T.
// Block: 256 rows (b,tpp,n-chunk), all 1152 cols via 12 RUNTIME passes of
// 96 cols each (pass p covers global cols [96p, 96p+96) = o-groups {2p,2p+1}).
// 8 waves: wm=w>>1 -> 64-row slice; wn=w&1 -> o-group 2p+wn (48 cols: 3 convs
// x 16 o) -> GLU triple lane-local, acc[4][3] = 48 VGPR live per iteration.
// LDS: A[256][192] 96 KB staged once + W chunk dbuf 2 x 12 KB = 120 KB.
// Chunk (p,ks) parity = (p+ks)&1; next chunk prefetched during compute.
__global__ __launch_bounds__(512) void tc2_kernel(const bf16* __restrict__ Tg,
                                                  const bf16* __restrict__ W2c,
                                                  const float* __restrict__ b1,
                                                  const float* __restrict__ b2,
                                                  const float* __restrict__ b3,
                                                  float* __restrict__ nsum,
                                                  float* __restrict__ nsq,
                                                  bf16* __restrict__ slice) {
  __shared__ __align__(16) char smem[122880];  // A 96K + 2 x W 12K
  bf16* Asm = (bf16*)smem;
  const int rb = blockIdx.x;                   // 512 blocks: b(16) x tpp(8) x nch(4)
  const int b = rb >> 5, tpp = (rb >> 2) & 7, n0 = (rb & 3) << 8;
  const int tid = threadIdx.x, lane = tid & 63, w = tid >> 6;
  const int wm = w >> 1, wn = w & 1;
  const int colL = lane & 15, kg = lane >> 4;
  const int rxor = colL & 7;

  // ---- stage A once: 96 KB; wave w stages bytes [w*12288, +12288)
  #pragma unroll
  for (int i = 0; i < 12; i++) {
    int fb = w * 12288 + i * 1024 + lane * 16;  // byte offset in A region
    int row = fb / 384;                          // 384 B per row (192 bf16)
    int s = (fb % 384) >> 4;                     // slot 0..23
    int koff = (s & ~7) * 8 + (((s & 7) ^ (row & 7)) << 3);
    lds_load16(&Tg[(size_t)((n0 + row) * 16 + b) * 640 + tpp * 64 + koff],
               (bf16*)(smem + w * 12288 + i * 1024));
  }
  // ---- W chunk stager: 12 KB = [96 cols][64 k], rows of 8 slots.
  // 12 x 1024B segments; wave w takes seg w (+ seg w+8 for w<4).
  auto stageW = [&](int colBase, int ks, int buf) {
    {
      int lc = w * 8 + (lane >> 3);
      int cg = colBase + lc;
      int ksrc = ks * 64 + (((lane & 7) ^ (cg & 7)) << 3);
      lds_load16(&W2c[(size_t)cg * 192 + ksrc],
                 (bf16*)(smem + 98304 + buf * 12288 + w * 1024));
    }
    if (w < 4) {
      int s2 = w + 8;
      int lc = s2 * 8 + (lane >> 3);
      int cg = colBase + lc;
      int ksrc = ks * 64 + (((lane & 7) ^ (cg & 7)) << 3);
      lds_load16(&W2c[(size_t)cg * 192 + ksrc],
                 (bf16*)(smem + 98304 + buf * 12288 + s2 * 1024));
    }
  };
  stageW(0, 0, 0);
  __syncthreads();                             // A + chunk0 ready

  float ssum[4][4], ssq[4][4];
  #pragma unroll
  for (int mt = 0; mt < 4; mt++)
    #pragma unroll
    for (int r = 0; r < 4; r++) { ssum[mt][r] = 0.0f; ssq[mt][r] = 0.0f; }

  #pragma unroll 1
  for (int pass = 0; pass < 12; pass++) {      // RUNTIME loop: small live set
    const int colBase = pass * 96;
    const int pb = pass & 1;

    f32x4 acc[4][3];
    #pragma unroll
    for (int i = 0; i < 4; i++)
      #pragma unroll
      for (int j = 0; j < 3; j++) acc[i][j] = splat4(0.0f);

    #pragma unroll
    for (int ks = 0; ks < 3; ks++) {
      const int bufCur = pb ^ (ks & 1);
      if (pass < 11 || ks < 2) {               // prefetch next chunk
        if (ks < 2) stageW(colBase, ks + 1, bufCur ^ 1);
        else        stageW(colBase + 96, 0, bufCur ^ 1);
      }
      const bf16* Wsb = (const bf16*)(smem + 98304 + bufCur * 12288);
      #pragma unroll
      for (int kk = 0; kk < 2; kk++) {
        bf16x8 af[4], bfr[3];
        #pragma unroll
        for (int mt = 0; mt < 4; mt++)
          af[mt] = *(const bf16x8*)(&Asm[(wm * 64 + mt * 16 + colL) * 192 + ks * 64 +
                                         (((kk * 4 + kg) ^ rxor) << 3)]);
        #pragma unroll
        for (int j = 0; j < 3; j++)
          bfr[j] = *(const bf16x8*)(&Wsb[(wn * 48 + j * 16 + colL) * 64 +
                                         (((kk * 4 + kg) ^ rxor) << 3)]);
        #pragma unroll
        for (int mt = 0; mt < 4; mt++)
          #pragma unroll
          for (int j = 0; j < 3; j++)
            acc[mt][j] = mfma16(af[mt], bfr[j], acc[mt][j]);
      }
      __syncthreads();                         // chunk p+1 arrived; bufs free
    }

    // GLU epilogue for this pass: one og per wave (og = 2*pass + wn)
    const int o = ((pass * 2 + wn) << 4) + colL;
    const float bv1 = b1[o], bv2 = b2[o], bv3 = b3[o];
    #pragma unroll
    for (int mt = 0; mt < 4; mt++)
      #pragma unroll
      for (int r = 0; r < 4; r++) {
        float pv = acc[mt][0][r] + bv1;
        float qv = acc[mt][1][r] + bv2;
        float rv = acc[mt][2][r] + bv3;
        float h = pv * (1.0f / (1.0f + __expf(-qv))) + rv;
        h = h > 0.0f ? h : 0.0f;
        ssum[mt][r] += h;
        ssq[mt][r] += h * h;
        if (tpp == 7) {
          int n = n0 + wm * 64 + mt * 16 + kg * 4 + r;
          slice[(size_t)((b << 10) + n) * 384 + o] = (bf16)h;
        }
      }
  }

  // reduce over colL (16 lanes) -> LDS -> 2 atomics per row (256 rows)
  float* sred = (float*)smem;                  // alias A region (done with it)
  sred[tid] = 0.0f;                            // 512 floats = [256][2]
  __syncthreads();
  #pragma unroll
  for (int mt = 0; mt < 4; mt++)
    #pragma unroll
    for (int r = 0; r < 4; r++) {
      float s = ssum[mt][r], q = ssq[mt][r];
      #pragma unroll
      for (int d = 1; d < 16; d <<= 1) {
        s += __shfl_xor(s, d);
        q += __shfl_xor(q, d);
      }
      if (colL == 0) {
        int rl = wm * 64 + mt * 16 + kg * 4 + r;   // local row [0,256)
        atomicAdd(&sred[rl * 2], s);
        atomicAdd(&sred[rl * 2 + 1], q);
      }
    }
  __syncthreads();
  if (tid < 256) {
    atomicAdd(&nsum[n0 + tid], sred[tid * 2]);
    atomicAdd(&nsq[n0 + tid], sred[tid * 2 + 1]);
  }
}

// ----------------------------- BN finalize ---------------------------------
__global__ __launch_bounds__(256) void bnstat_kernel(const float* __restrict__ nsum,
                                                     const float* __restrict__ nsq,
                                                     const float* __restrict__ gamma,
                                                     const float* __restrict__ beta,
                                                     float* __restrict__ scoff) {
  int n = blockIdx.x * 256 + threadIdx.x;       // 1024 exact
  const float inv_cnt = 1.0f / 49152.0f;        // B*8*384
  float m = nsum[n] * inv_cnt;
  float var = nsq[n] * inv_cnt - m * m;
  float sc = rsqrtf(var + 1e-5f) * gamma[n];
  scoff[n] = sc;
  scoff[1024 + n] = beta[n] - m * sc;
}

// out[f], f = c*16384 + b*1024 + n  (== reshape(T,B,N,OUT) flat order)
__global__ __launch_bounds__(256) void final_kernel(const bf16* __restrict__ slice,
                                                    const float* __restrict__ scoff,
                                                    float* __restrict__ out) {
  int f = blockIdx.x * 256 + threadIdx.x;       // 6291456 exact
  int c = f >> 14, rem = f & 16383;
  int b = rem >> 10, n = rem & 1023;
  out[f] = (float)slice[(size_t)((b << 10) + n) * 384 + c] * scoff[n] + scoff[1024 + n];
}

// ---------------------------------------------------------------------------
extern "C" void kernel_launch(void* const* d_in, const int* in_sizes, int n_in,
                              void* d_out, int out_size, void* d_ws, size_t ws_size,
                              hipStream_t stream) {
  const float* X    = (const float*)d_in[0];
  const int*   ei   = (const int*)d_in[1];
  const float* ew   = (const float*)d_in[2];
  const float* t1w1 = (const float*)d_in[3];
  const float* t1b1 = (const float*)d_in[4];
  const float* t1w2 = (const float*)d_in[5];
  const float* t1b2 = (const float*)d_in[6];
  const float* t1w3 = (const float*)d_in[7];
  const float* t1b3 = (const float*)d_in[8];
  const float* chebW = (const float*)d_in[9];
  const float* chebB = (const float*)d_in[10];
  const float* t2w1 = (const float*)d_in[11];
  const float* t2b1 = (const float*)d_in[12];
  const float* t2w2 = (const float*)d_in[13];
  const float* t2b2 = (const float*)d_in[14];
  const float* t2w3 = (const float*)d_in[15];
  const float* t2b3 = (const float*)d_in[16];
  const float* gamma = (const float*)d_in[17];
  const float* beta  = (const float*)d_in[18];
  float* out = (float*)d_out;

  char* ws = (char*)d_ws;
  float* Lf    = (float*)(ws);                  // 4 MB dense L (fp32 scatter target)
  float* deg   = (float*)(ws + 4194304);
  float* nsum  = (float*)(ws + 4198400);
  float* nsq   = (float*)(ws + 4202496);
  bf16*  Lbf   = (bf16*)(ws + 4210688);         // 2 MB
  bf16*  zf    = (bf16*)(ws + 6307840);         // 20 MB feature-major z
  bf16*  P1f   = (bf16*)(ws + 27279360);        // 20 MB
  bf16*  P2f   = (bf16*)(ws + 48250880);        // 20 MB
  bf16*  Tg    = (bf16*)(ws + 69222400);        // 20 MB node-major
  float* Wc    = (float*)(ws + 90193920);       // 48 KB combined cheb weights
  bf16*  W2c   = (bf16*)(ws + 90243072);        // 432 KB tc2 weights [col][k]
  bf16*  slice = (bf16*)(ws + 90685440);        // 12 MB t''=7 slice
  float* scoff = (float*)(ws + 103268352);      // 8 KB

  hipMemsetAsync(ws, 0, 4206592, stream);       // Lf + deg + nsum + nsq

  wprep_kernel<<<912, 256, 0, stream>>>(chebW, t2w1, t2w2, t2w3, Wc, W2c);
  tc1_kernel<<<dim3(4, 10240), 256, 0, stream>>>(X, t1w1, t1b1, t1w2, t1b2, t1w3, t1b3, zf);
  deg_kernel<<<64, 256, 0, stream>>>(ei, ew, deg);
  scatterL_kernel<<<64, 256, 0, stream>>>(ei, ew, deg, Lf);
  cvtL_kernel<<<4096, 256, 0, stream>>>(Lf, Lbf);
  gemm_bt<<<dim3(8, 80), 256, 0, stream>>>(zf, Lbf, P1f, 10240, 1024, 1024);
  gemm_bt<<<dim3(8, 80), 256, 0, stream>>>(P1f, Lbf, P2f, 10240, 1024, 1024);
  combine_kernel<<<dim3(16, 160), 256, 0, stream>>>(zf, P1f, P2f, Wc, chebB, Tg);
  tc2_kernel<<<512, 512, 0, stream>>>(Tg, W2c, t2b1, t2b2, t2b3, nsum, nsq, slice);
  bnstat_kernel<<<4, 256, 0, stream>>>(nsum, nsq, gamma, beta, scoff);
  final_kernel<<<24576, 256, 0, stream>>>(slice, scoff, out);
}